// Round 4
// baseline (1390.633 us; speedup 1.0000x reference)
//
#include <hip/hip_runtime.h>
#include <hip/hip_bf16.h>

#define NODES 100000
#define BN_EPS 1e-5f
#define NB 512          // buckets
#define NPB 196         // nodes per bucket (512*196 = 100352 >= 100000)
#define EPB 16384       // edges per hist/place block

// ---------------------------------------------------------------------------
// K1: Fn[n][c] = sum_ci w_n[c][ci] * x[ci][n].  Output node-major [n][c] so
// the bucket-reduce gather reads 256B-contiguous rows.
// ---------------------------------------------------------------------------
__global__ __launch_bounds__(256) void k_gemm_n(
        const float* __restrict__ x, const float* __restrict__ wn,
        float* __restrict__ Fn) {
    __shared__ float lx[64][65];
    __shared__ float lw[64][65];
    const int t = threadIdx.x;
    const int n0 = blockIdx.x * 64;
    for (int idx = t; idx < 4096; idx += 256) {
        int r = idx >> 6, q = idx & 63;
        lw[r][q] = wn[idx];
        int n = n0 + q;
        lx[r][q] = (n < NODES) ? x[r * NODES + n] : 0.f;
    }
    __syncthreads();
    const int c = t & 63;
    const int jb = t >> 6;
    for (int k = 0; k < 16; ++k) {
        int j = jb + 4 * k;
        int n = n0 + j;
        if (n >= NODES) continue;
        float acc = 0.f;
#pragma unroll
        for (int ci = 0; ci < 64; ++ci)
            acc += lw[c][ci] * lx[ci][j];
        Fn[n * 64 + c] = acc;
    }
}

// ---------------------------------------------------------------------------
// Bucket histogram: LDS-aggregated per block (16384 edges), 512 global
// atomics per block -> ~200 per counter total. No contention issue.
// ---------------------------------------------------------------------------
__global__ __launch_bounds__(256) void k_hist_b(
        const int* __restrict__ ridx, int* __restrict__ hist, int E) {
    __shared__ int lh[NB];
    const int t = threadIdx.x;
    lh[t] = 0; lh[t + 256] = 0;
    __syncthreads();
    const long long base = (long long)blockIdx.x * EPB;
    for (int k = 0; k < 64; ++k) {
        long long e = base + t + k * 256;
        if (e < E) atomicAdd(&lh[(unsigned)ridx[e] / NPB], 1);
    }
    __syncthreads();
    if (lh[t])       atomicAdd(&hist[t], lh[t]);
    if (lh[t + 256]) atomicAdd(&hist[t + 256], lh[t + 256]);
}

// 512-wide exclusive scan, one block.
__global__ __launch_bounds__(512) void k_scan_b(
        const int* __restrict__ hist, int* __restrict__ start,
        int* __restrict__ cursor) {
    __shared__ int a[NB];
    const int t = threadIdx.x;
    a[t] = hist[t];
    __syncthreads();
    for (int off = 1; off < NB; off <<= 1) {
        int v = a[t];
        int add = (t >= off) ? a[t - off] : 0;
        __syncthreads();
        a[t] = v + add;
        __syncthreads();
    }
    int ex = (t == 0) ? 0 : a[t - 1];
    start[t] = ex;
    cursor[t] = ex;
    if (t == NB - 1) start[NB] = a[NB - 1];
}

// ---------------------------------------------------------------------------
// Placement: per block LDS hist -> claim global ranges -> write packed
// (rloc<<17 | g) u32 per edge into bucket-contiguous order. 512 write
// streams -> full-line writebacks, ~14 MB total.
// ---------------------------------------------------------------------------
__global__ __launch_bounds__(256) void k_place(
        const int* __restrict__ ridx, const int* __restrict__ gidx,
        int* __restrict__ cursor, unsigned* __restrict__ packed, int E) {
    __shared__ int lh[NB];
    __shared__ int lbase[NB];
    const int t = threadIdx.x;
    lh[t] = 0; lh[t + 256] = 0;
    __syncthreads();
    const long long base = (long long)blockIdx.x * EPB;
    for (int k = 0; k < 64; ++k) {
        long long e = base + t + k * 256;
        if (e < E) atomicAdd(&lh[(unsigned)ridx[e] / NPB], 1);
    }
    __syncthreads();
    for (int b = t; b < NB; b += 256) {
        int c = lh[b];
        lbase[b] = c ? atomicAdd(&cursor[b], c) : 0;
        lh[b] = 0;  // reuse as intra-block cursor
    }
    __syncthreads();
    for (int k = 0; k < 64; ++k) {
        long long e = base + t + k * 256;
        if (e < E) {
            unsigned r = (unsigned)ridx[e];
            unsigned b = r / NPB;
            int off = atomicAdd(&lh[b], 1);
            packed[lbase[b] + off] = ((r - b * NPB) << 17) | (unsigned)gidx[e];
        }
    }
}

// ---------------------------------------------------------------------------
// Bucket reduce: one 1024-thread block per bucket. sums[196][64] in LDS
// (50KB, 2 blocks/CU = 32 waves). Per edge: wave-uniform packed load, 256B
// contiguous Fn gather, LDS-atomic f32 add (2-way bank aliasing = free).
// Writes divided mean [n][c] coalesced. Zero global atomics.
// ---------------------------------------------------------------------------
__global__ __launch_bounds__(1024) void k_reduce_b(
        const float* __restrict__ Fn, const unsigned* __restrict__ packed,
        const int* __restrict__ start, float* __restrict__ mean) {
    __shared__ float ls[NPB * 64];
    __shared__ int lcnt[NPB];
    const int t = threadIdx.x;
    const int b = blockIdx.x;
    for (int i = t; i < NPB * 64; i += 1024) ls[i] = 0.f;
    if (t < NPB) lcnt[t] = 0;
    __syncthreads();
    const int s0 = start[b], s1 = start[b + 1];
    const int w = t >> 6, lane = t & 63;
    const int chunk = (s1 - s0 + 15) >> 4;
    int i = s0 + w * chunk;
    int end = min(i + chunk, s1);
    for (; i + 3 < end; i += 4) {
        unsigned p0 = packed[i],     p1 = packed[i + 1];
        unsigned p2 = packed[i + 2], p3 = packed[i + 3];
        float f0 = Fn[(p0 & 0x1FFFFu) * 64 + lane];
        float f1 = Fn[(p1 & 0x1FFFFu) * 64 + lane];
        float f2 = Fn[(p2 & 0x1FFFFu) * 64 + lane];
        float f3 = Fn[(p3 & 0x1FFFFu) * 64 + lane];
        atomicAdd(&ls[(p0 >> 17) * 64 + lane], f0);
        atomicAdd(&ls[(p1 >> 17) * 64 + lane], f1);
        atomicAdd(&ls[(p2 >> 17) * 64 + lane], f2);
        atomicAdd(&ls[(p3 >> 17) * 64 + lane], f3);
        if (lane == 0) {
            atomicAdd(&lcnt[p0 >> 17], 1); atomicAdd(&lcnt[p1 >> 17], 1);
            atomicAdd(&lcnt[p2 >> 17], 1); atomicAdd(&lcnt[p3 >> 17], 1);
        }
    }
    for (; i < end; ++i) {
        unsigned p = packed[i];
        atomicAdd(&ls[(p >> 17) * 64 + lane], Fn[(p & 0x1FFFFu) * 64 + lane]);
        if (lane == 0) atomicAdd(&lcnt[p >> 17], 1);
    }
    __syncthreads();
    const long long nb = (long long)b * NPB;
    for (int idx = t; idx < NPB * 64; idx += 1024) {
        int rl = idx >> 6;
        long long n = nb + rl;
        if (n < NODES)
            mean[n * 64 + (idx & 63)] = ls[idx] / fmaxf((float)lcnt[rl], 1.f);
    }
}

// ---------------------------------------------------------------------------
// K3: recompute Fv = w_v @ x, add mean (or sums/cnt in fallback mode),
// transpose to [c][n] into d_out, accumulate per-channel sum/sumsq into bn.
// ---------------------------------------------------------------------------
__global__ __launch_bounds__(256) void k_combine(
        const float* __restrict__ x, const float* __restrict__ wv,
        const float* __restrict__ sums, const int* __restrict__ counts,
        const int divide,
        float* __restrict__ outpre, float* __restrict__ bn) {
    __shared__ float lx[64][65];
    __shared__ float lw[64][65];
    __shared__ float tile[64][65];
    __shared__ float reds[64][4];
    __shared__ float redq[64][4];
    const int t = threadIdx.x;
    const int n0 = blockIdx.x * 64;
    for (int idx = t; idx < 4096; idx += 256) {
        int r = idx >> 6, q = idx & 63;
        lw[r][q] = wv[idx];
        int n = n0 + q;
        lx[r][q] = (n < NODES) ? x[r * NODES + n] : 0.f;
    }
    __syncthreads();
    const int c = t & 63;
    const int jb = t >> 6;
    float ls = 0.f, lq = 0.f;
    for (int k = 0; k < 16; ++k) {
        int j = jb + 4 * k;
        int n = n0 + j;
        float v = 0.f;
        if (n < NODES) {
            float fv = 0.f;
#pragma unroll
            for (int ci = 0; ci < 64; ++ci)
                fv += lw[c][ci] * lx[ci][j];
            v = sums[n * 64 + c];
            if (divide) v /= fmaxf((float)counts[n], 1.f);
            v += fv;
            ls += v;
            lq += v * v;
        }
        tile[c][j] = v;
    }
    reds[c][jb] = ls;
    redq[c][jb] = lq;
    __syncthreads();
    const int j2 = t & 63;
    const int c2 = t >> 6;
    const int n = n0 + j2;
    if (n < NODES) {
        for (int k = 0; k < 16; ++k) {
            int cc = c2 + 4 * k;
            outpre[cc * NODES + n] = tile[cc][j2];
        }
    }
    if (t < 64) {
        atomicAdd(&bn[t],      reds[t][0] + reds[t][1] + reds[t][2] + reds[t][3]);
        atomicAdd(&bn[64 + t], redq[t][0] + redq[t][1] + redq[t][2] + redq[t][3]);
    }
}

// K4: per-channel affine from batch stats + PReLU, in place on d_out [C][N].
__global__ __launch_bounds__(256) void k_final(
        float* __restrict__ out, const float* __restrict__ bn,
        const float* __restrict__ gamma, const float* __restrict__ beta,
        const float* __restrict__ pa) {
    const int c = blockIdx.y;
    const int n = blockIdx.x * 256 + threadIdx.x;
    const float invN = 1.f / (float)NODES;
    float mu = bn[c] * invN;
    float var = fmaxf(bn[64 + c] * invN - mu * mu, 0.f);
    float scale = gamma[c] * rsqrtf(var + BN_EPS);
    float shift = beta[c] - mu * scale;
    float a = pa[0];
    if (n < NODES) {
        float y = out[c * NODES + n] * scale + shift;
        y = (y >= 0.f) ? y : a * y;
        out[c * NODES + n] = y;
    }
}

// Fallback (ws too small): round-2 atomic scatter, proven correct.
__global__ __launch_bounds__(256) void k_scatter(
        const float* __restrict__ Fn,
        const int* __restrict__ gidx, const int* __restrict__ ridx,
        float* __restrict__ sums, int* __restrict__ counts, int E) {
    const int wave = (int)((blockIdx.x * blockDim.x + threadIdx.x) >> 6);
    const int lane = threadIdx.x & 63;
    const int base = wave * 64;
    if (base >= E) return;
    const int nvalid = min(64, E - base);
    int g = 0, r = 0;
    if (lane < nvalid) {
        g = gidx[base + lane];
        r = ridx[base + lane];
        atomicAdd(&counts[r], 1);
    }
    for (int i = 0; i < nvalid; ++i) {
        int gg = __shfl(g, i);
        int rr = __shfl(r, i);
        float v = Fn[gg * 64 + lane];
        atomicAdd(&sums[rr * 64 + lane], v);
    }
}

extern "C" void kernel_launch(void* const* d_in, const int* in_sizes, int n_in,
                              void* d_out, int out_size, void* d_ws, size_t ws_size,
                              hipStream_t stream) {
    const float* x     = (const float*)d_in[0];
    const float* w_v   = (const float*)d_in[1];
    const float* w_n   = (const float*)d_in[2];
    const float* gamma = (const float*)d_in[3];
    const float* beta  = (const float*)d_in[4];
    const float* pa    = (const float*)d_in[5];
    const int* ridx    = (const int*)d_in[6];
    const int* gidx    = (const int*)d_in[7];
    float* out = (float*)d_out;

    const int E = in_sizes[6];
    const long long N64 = (long long)NODES * 64;
    const int ntiles = (NODES + 63) / 64;
    const dim3 g4((NODES + 255) / 256, 64);
    const int nblk_e = (E + EPB - 1) / EPB;

    // Bucket-path ws: mean[N64] f32 | packed[E] u32 | hist[512] | start[513] |
    //                 cursor[512] | bn[128]
    size_t need = ((size_t)N64 + (size_t)E + NB + (NB + 1) + NB + 128) * 4;

    if (ws_size >= need) {
        float*    mean   = (float*)d_ws;
        unsigned* packed = (unsigned*)(mean + N64);
        int*      hist   = (int*)(packed + E);
        int*      start  = hist + NB;
        int*      cursor = start + NB + 1;
        float*    bn     = (float*)(cursor + NB);
        float* Fn = out;  // staged in d_out; dead after k_reduce_b

        // zero hist..bn (contiguous small tail)
        hipMemsetAsync(hist, 0, (size_t)(NB + (NB + 1) + NB + 128) * 4, stream);

        k_hist_b<<<nblk_e, 256, 0, stream>>>(ridx, hist, E);
        k_scan_b<<<1, 512, 0, stream>>>(hist, start, cursor);
        k_place<<<nblk_e, 256, 0, stream>>>(ridx, gidx, cursor, packed, E);
        k_gemm_n<<<ntiles, 256, 0, stream>>>(x, w_n, Fn);
        k_reduce_b<<<NB, 1024, 0, stream>>>(Fn, packed, start, mean);
        k_combine<<<ntiles, 256, 0, stream>>>(x, w_v, mean, (const int*)d_ws, 0,
                                              out, bn);
        k_final<<<g4, 256, 0, stream>>>(out, bn, gamma, beta, pa);
    } else {
        // Fallback: atomic-scatter path (26.0 MB ws).
        float* sums   = (float*)d_ws;
        int*   counts = (int*)(sums + N64);
        float* bn     = (float*)(sums + N64 + NODES);
        float* Fn = out;

        hipMemsetAsync(sums, 0, (size_t)(N64 + NODES + 128) * sizeof(float),
                       stream);
        k_gemm_n<<<ntiles, 256, 0, stream>>>(x, w_n, Fn);
        k_scatter<<<(E + 255) / 256, 256, 0, stream>>>(Fn, gidx, ridx, sums,
                                                       counts, E);
        k_combine<<<ntiles, 256, 0, stream>>>(x, w_v, sums, counts, 1, out, bn);
        k_final<<<g4, 256, 0, stream>>>(out, bn, gamma, beta, pa);
    }
}

// Round 5
// 411.928 us; speedup vs baseline: 3.3759x; 3.3759x over previous
//
#include <hip/hip_runtime.h>
#include <hip/hip_bf16.h>

#define NODES 100000
#define BN_EPS 1e-5f
#define NB 1024         // buckets
#define NPB 98          // nodes per bucket (1024*98 = 100352 >= 100000)
#define EPB 16384       // edges per hist/place block
#define SCAP 4608       // bucket sort LDS capacity (avg 3125, +26 sigma)

__device__ __forceinline__ unsigned bf16rne(float f) {
    unsigned u = __float_as_uint(f);
    u += 0x7FFFu + ((u >> 16) & 1u);
    return u >> 16;
}
__device__ __forceinline__ float bflo(unsigned u) { return __uint_as_float(u << 16); }
__device__ __forceinline__ float bfhi(unsigned u) { return __uint_as_float(u & 0xFFFF0000u); }

// ---------------------------------------------------------------------------
// GEMM producing packed-bf16 Fn: Fnh2[n*32 + c/2] = (bf16(c+1)<<16)|bf16(c).
// ---------------------------------------------------------------------------
__global__ __launch_bounds__(256) void k_gemm_bf16(
        const float* __restrict__ x, const float* __restrict__ wn,
        unsigned* __restrict__ Fnh2) {
    __shared__ float lx[64][65];
    __shared__ float lw[64][65];
    const int t = threadIdx.x;
    const int n0 = blockIdx.x * 64;
    for (int idx = t; idx < 4096; idx += 256) {
        int r = idx >> 6, q = idx & 63;
        lw[r][q] = wn[idx];
        int n = n0 + q;
        lx[r][q] = (n < NODES) ? x[r * NODES + n] : 0.f;
    }
    __syncthreads();
    const int c = t & 63;
    const int jb = t >> 6;
    for (int k = 0; k < 16; ++k) {
        int j = jb + 4 * k;
        int n = n0 + j;
        if (n >= NODES) continue;
        float acc = 0.f;
#pragma unroll
        for (int ci = 0; ci < 64; ++ci)
            acc += lw[c][ci] * lx[ci][j];
        float partner = __shfl_xor(acc, 1);
        if (!(c & 1))
            Fnh2[n * 32 + (c >> 1)] = bf16rne(acc) | (bf16rne(partner) << 16);
    }
}

// fp32 Fn variant (fallback path only)
__global__ __launch_bounds__(256) void k_gemm_n(
        const float* __restrict__ x, const float* __restrict__ wn,
        float* __restrict__ Fn) {
    __shared__ float lx[64][65];
    __shared__ float lw[64][65];
    const int t = threadIdx.x;
    const int n0 = blockIdx.x * 64;
    for (int idx = t; idx < 4096; idx += 256) {
        int r = idx >> 6, q = idx & 63;
        lw[r][q] = wn[idx];
        int n = n0 + q;
        lx[r][q] = (n < NODES) ? x[r * NODES + n] : 0.f;
    }
    __syncthreads();
    const int c = t & 63;
    const int jb = t >> 6;
    for (int k = 0; k < 16; ++k) {
        int j = jb + 4 * k;
        int n = n0 + j;
        if (n >= NODES) continue;
        float acc = 0.f;
#pragma unroll
        for (int ci = 0; ci < 64; ++ci)
            acc += lw[c][ci] * lx[ci][j];
        Fn[n * 64 + c] = acc;
    }
}

// ---------------------------------------------------------------------------
// Bucket histogram (LDS-aggregated).
// ---------------------------------------------------------------------------
__global__ __launch_bounds__(256) void k_hist_b(
        const int* __restrict__ ridx, int* __restrict__ hist, int E) {
    __shared__ int lh[NB];
    const int t = threadIdx.x;
#pragma unroll
    for (int k = 0; k < 4; ++k) lh[t + 256 * k] = 0;
    __syncthreads();
    const long long base = (long long)blockIdx.x * EPB;
    for (int k = 0; k < 64; ++k) {
        long long e = base + t + k * 256;
        if (e < E) atomicAdd(&lh[(unsigned)ridx[e] / NPB], 1);
    }
    __syncthreads();
#pragma unroll
    for (int k = 0; k < 4; ++k) {
        int v = lh[t + 256 * k];
        if (v) atomicAdd(&hist[t + 256 * k], v);
    }
}

// 1024-wide exclusive scan, one block.
__global__ __launch_bounds__(1024) void k_scan_b(
        const int* __restrict__ hist, int* __restrict__ start,
        int* __restrict__ cursor) {
    __shared__ int a[NB];
    const int t = threadIdx.x;
    a[t] = hist[t];
    __syncthreads();
    for (int off = 1; off < NB; off <<= 1) {
        int v = a[t];
        int add = (t >= off) ? a[t - off] : 0;
        __syncthreads();
        a[t] = v + add;
        __syncthreads();
    }
    int ex = (t == 0) ? 0 : a[t - 1];
    start[t] = ex;
    cursor[t] = ex;
    if (t == NB - 1) start[NB] = a[NB - 1];
}

// ---------------------------------------------------------------------------
// Placement: packed[pos] = (rloc<<17)|g in bucket-contiguous order.
// ---------------------------------------------------------------------------
__global__ __launch_bounds__(256) void k_place(
        const int* __restrict__ ridx, const int* __restrict__ gidx,
        int* __restrict__ cursor, unsigned* __restrict__ packed, int E) {
    __shared__ int lh[NB];
    __shared__ int lbase[NB];
    const int t = threadIdx.x;
#pragma unroll
    for (int k = 0; k < 4; ++k) lh[t + 256 * k] = 0;
    __syncthreads();
    const long long base = (long long)blockIdx.x * EPB;
    for (int k = 0; k < 64; ++k) {
        long long e = base + t + k * 256;
        if (e < E) atomicAdd(&lh[(unsigned)ridx[e] / NPB], 1);
    }
    __syncthreads();
    for (int b = t; b < NB; b += 256) {
        int c = lh[b];
        lbase[b] = c ? atomicAdd(&cursor[b], c) : 0;
        lh[b] = 0;  // reuse as intra-block cursor
    }
    __syncthreads();
    for (int k = 0; k < 64; ++k) {
        long long e = base + t + k * 256;
        if (e < E) {
            unsigned r = (unsigned)ridx[e];
            unsigned b = r / NPB;
            int off = atomicAdd(&lh[b], 1);
            packed[lbase[b] + off] = ((r - b * NPB) << 17) | (unsigned)gidx[e];
        }
    }
}

// ---------------------------------------------------------------------------
// Bucket-local sort (in place): packed[bucket range] becomes g sorted by
// local node; writes nodeptr (global CSR offsets). One block per bucket.
// ---------------------------------------------------------------------------
__global__ __launch_bounds__(512) void k_sortb(
        const int* __restrict__ start, unsigned* __restrict__ packed,
        int* __restrict__ nodeptr) {
    __shared__ unsigned lbuf[SCAP];
    __shared__ int lh[128];
    __shared__ int lsc[128];
    const int b = blockIdx.x, t = threadIdx.x;
    const int s0 = start[b];
    int cnt = start[b + 1] - s0;
    if (cnt > SCAP) cnt = SCAP;   // p ~ 0 guard against LDS overflow
    unsigned r[(SCAP + 511) / 512];
    int nr = 0;
    for (int k = t; k < cnt; k += 512) r[nr++] = packed[s0 + k];
    if (t < 128) lh[t] = 0;
    __syncthreads();
    for (int k = 0; k < nr; ++k) atomicAdd(&lh[r[k] >> 17], 1);
    __syncthreads();
    if (t < 128) lsc[t] = lh[t];
    __syncthreads();
    for (int off = 1; off < 128; off <<= 1) {
        int v = 0;
        if (t < 128) { v = lsc[t]; if (t >= off) v += lsc[t - off]; }
        __syncthreads();
        if (t < 128) lsc[t] = v;
        __syncthreads();
    }
    int excl = (t > 0 && t < 128) ? lsc[t - 1] : 0;
    __syncthreads();
    if (t < 128) lh[t] = excl;    // lh becomes the scatter cursor
    if (t < NPB) {
        long long n = (long long)b * NPB + t;
        if (n <= NODES) nodeptr[n] = s0 + excl;
    }
    __syncthreads();
    for (int k = 0; k < nr; ++k) {
        unsigned v = r[k];
        int pos = atomicAdd(&lh[v >> 17], 1);
        lbuf[pos] = v & 0x1FFFFu;
    }
    __syncthreads();
    for (int k = t; k < cnt; k += 512) packed[s0 + k] = lbuf[k];
}

// ---------------------------------------------------------------------------
// Pull segment-mean: one wave per node, 2 edges per gather instruction
// (half-wave = 32 lanes x bf16x2 = one 128B row), 8 edges in flight.
// ---------------------------------------------------------------------------
__global__ __launch_bounds__(256) void k_segreduce(
        const unsigned* __restrict__ Fnh2, const unsigned* __restrict__ packed,
        const int* __restrict__ nodeptr, float2* __restrict__ mean2) {
    const int n = (int)((blockIdx.x * 256u + threadIdx.x) >> 6);
    if (n >= NODES) return;
    const int lane = threadIdx.x & 63;
    const int sub = lane >> 5;       // half-wave: which of the 2 edges
    const int cp = lane & 31;        // channel pair
    const int s0 = nodeptr[n], s1 = nodeptr[n + 1];
    float ax = 0.f, ay = 0.f;
    int i = s0;
    for (; i + 7 < s1; i += 8) {
        int g0 = (int)packed[i     + sub];
        int g1 = (int)packed[i + 2 + sub];
        int g2 = (int)packed[i + 4 + sub];
        int g3 = (int)packed[i + 6 + sub];
        unsigned u0 = Fnh2[g0 * 32 + cp];
        unsigned u1 = Fnh2[g1 * 32 + cp];
        unsigned u2 = Fnh2[g2 * 32 + cp];
        unsigned u3 = Fnh2[g3 * 32 + cp];
        ax += bflo(u0) + bflo(u1) + bflo(u2) + bflo(u3);
        ay += bfhi(u0) + bfhi(u1) + bfhi(u2) + bfhi(u3);
    }
    for (; i < s1; i += 2) {
        if (i + sub < s1) {
            unsigned u = Fnh2[(int)packed[i + sub] * 32 + cp];
            ax += bflo(u);
            ay += bfhi(u);
        }
    }
    ax += __shfl_xor(ax, 32);
    ay += __shfl_xor(ay, 32);
    if (sub == 0) {
        float inv = 1.f / fmaxf((float)(s1 - s0), 1.f);
        float2 m; m.x = ax * inv; m.y = ay * inv;
        mean2[n * 32 + cp] = m;
    }
}

// ---------------------------------------------------------------------------
// Combine: recompute Fv = w_v @ x, add mean (or sums/cnt in fallback mode),
// transpose to [c][n] into d_out, per-channel sum/sumsq partials into bn.
// ---------------------------------------------------------------------------
__global__ __launch_bounds__(256) void k_combine(
        const float* __restrict__ x, const float* __restrict__ wv,
        const float* __restrict__ sums, const int* __restrict__ counts,
        const int divide,
        float* __restrict__ outpre, float* __restrict__ bn) {
    __shared__ float lx[64][65];
    __shared__ float lw[64][65];
    __shared__ float tile[64][65];
    __shared__ float reds[64][4];
    __shared__ float redq[64][4];
    const int t = threadIdx.x;
    const int n0 = blockIdx.x * 64;
    for (int idx = t; idx < 4096; idx += 256) {
        int r = idx >> 6, q = idx & 63;
        lw[r][q] = wv[idx];
        int n = n0 + q;
        lx[r][q] = (n < NODES) ? x[r * NODES + n] : 0.f;
    }
    __syncthreads();
    const int c = t & 63;
    const int jb = t >> 6;
    float ls = 0.f, lq = 0.f;
    for (int k = 0; k < 16; ++k) {
        int j = jb + 4 * k;
        int n = n0 + j;
        float v = 0.f;
        if (n < NODES) {
            float fv = 0.f;
#pragma unroll
            for (int ci = 0; ci < 64; ++ci)
                fv += lw[c][ci] * lx[ci][j];
            v = sums[n * 64 + c];
            if (divide) v /= fmaxf((float)counts[n], 1.f);
            v += fv;
            ls += v;
            lq += v * v;
        }
        tile[c][j] = v;
    }
    reds[c][jb] = ls;
    redq[c][jb] = lq;
    __syncthreads();
    const int j2 = t & 63;
    const int c2 = t >> 6;
    const int n = n0 + j2;
    if (n < NODES) {
        for (int k = 0; k < 16; ++k) {
            int cc = c2 + 4 * k;
            outpre[cc * NODES + n] = tile[cc][j2];
        }
    }
    if (t < 64) {
        atomicAdd(&bn[t],      reds[t][0] + reds[t][1] + reds[t][2] + reds[t][3]);
        atomicAdd(&bn[64 + t], redq[t][0] + redq[t][1] + redq[t][2] + redq[t][3]);
    }
}

// K4: per-channel affine from batch stats + PReLU, in place on d_out [C][N].
__global__ __launch_bounds__(256) void k_final(
        float* __restrict__ out, const float* __restrict__ bn,
        const float* __restrict__ gamma, const float* __restrict__ beta,
        const float* __restrict__ pa) {
    const int c = blockIdx.y;
    const int n = blockIdx.x * 256 + threadIdx.x;
    const float invN = 1.f / (float)NODES;
    float mu = bn[c] * invN;
    float var = fmaxf(bn[64 + c] * invN - mu * mu, 0.f);
    float scale = gamma[c] * rsqrtf(var + BN_EPS);
    float shift = beta[c] - mu * scale;
    float a = pa[0];
    if (n < NODES) {
        float y = out[c * NODES + n] * scale + shift;
        y = (y >= 0.f) ? y : a * y;
        out[c * NODES + n] = y;
    }
}

// Fallback (ws too small): round-2 atomic scatter, proven correct.
__global__ __launch_bounds__(256) void k_scatter(
        const float* __restrict__ Fn,
        const int* __restrict__ gidx, const int* __restrict__ ridx,
        float* __restrict__ sums, int* __restrict__ counts, int E) {
    const int wave = (int)((blockIdx.x * blockDim.x + threadIdx.x) >> 6);
    const int lane = threadIdx.x & 63;
    const int base = wave * 64;
    if (base >= E) return;
    const int nvalid = min(64, E - base);
    int g = 0, r = 0;
    if (lane < nvalid) {
        g = gidx[base + lane];
        r = ridx[base + lane];
        atomicAdd(&counts[r], 1);
    }
    for (int i = 0; i < nvalid; ++i) {
        int gg = __shfl(g, i);
        int rr = __shfl(r, i);
        float v = Fn[gg * 64 + lane];
        atomicAdd(&sums[rr * 64 + lane], v);
    }
}

extern "C" void kernel_launch(void* const* d_in, const int* in_sizes, int n_in,
                              void* d_out, int out_size, void* d_ws, size_t ws_size,
                              hipStream_t stream) {
    const float* x     = (const float*)d_in[0];
    const float* w_v   = (const float*)d_in[1];
    const float* w_n   = (const float*)d_in[2];
    const float* gamma = (const float*)d_in[3];
    const float* beta  = (const float*)d_in[4];
    const float* pa    = (const float*)d_in[5];
    const int* ridx    = (const int*)d_in[6];
    const int* gidx    = (const int*)d_in[7];
    float* out = (float*)d_out;

    const int E = in_sizes[6];
    const long long N64 = (long long)NODES * 64;
    const int ntiles = (NODES + 63) / 64;
    const dim3 g4((NODES + 255) / 256, 64);
    const int nblk_e = (E + EPB - 1) / EPB;

    // Main ws: mean[N64] f32 | packed[E] u32 | hist[NB] | bn[128] |
    //          start[NB+1] | cursor[NB] | nodeptr[NODES+1]      (~38.9 MB)
    size_t need = ((size_t)N64 + (size_t)E + NB + 128 + (NB + 1) + NB
                   + (NODES + 1)) * 4;

    if (ws_size >= need) {
        float*    mean    = (float*)d_ws;
        unsigned* packed  = (unsigned*)(mean + N64);
        int*      hist    = (int*)(packed + E);
        float*    bn      = (float*)(hist + NB);
        int*      start   = (int*)(bn + 128);
        int*      cursor  = start + NB + 1;
        int*      nodeptr = cursor + NB;
        unsigned* Fnh2 = (unsigned*)out;  // 12.8 MB staged in d_out

        hipMemsetAsync(hist, 0, (size_t)(NB + 128) * 4, stream);  // hist + bn

        k_hist_b<<<nblk_e, 256, 0, stream>>>(ridx, hist, E);
        k_scan_b<<<1, NB, 0, stream>>>(hist, start, cursor);
        k_place<<<nblk_e, 256, 0, stream>>>(ridx, gidx, cursor, packed, E);
        k_sortb<<<NB, 512, 0, stream>>>(start, packed, nodeptr);
        k_gemm_bf16<<<ntiles, 256, 0, stream>>>(x, w_n, Fnh2);
        k_segreduce<<<(NODES * 64 + 255) / 256, 256, 0, stream>>>(
            Fnh2, packed, nodeptr, (float2*)mean);
        k_combine<<<ntiles, 256, 0, stream>>>(x, w_v, mean, nodeptr, 0, out, bn);
        k_final<<<g4, 256, 0, stream>>>(out, bn, gamma, beta, pa);
    } else {
        // Fallback: atomic-scatter path (26.0 MB ws).
        float* sums   = (float*)d_ws;
        int*   counts = (int*)(sums + N64);
        float* bn     = (float*)(sums + N64 + NODES);
        float* Fn = out;

        hipMemsetAsync(sums, 0, (size_t)(N64 + NODES + 128) * sizeof(float),
                       stream);
        k_gemm_n<<<ntiles, 256, 0, stream>>>(x, w_n, Fn);
        k_scatter<<<(E + 255) / 256, 256, 0, stream>>>(Fn, gidx, ridx, sums,
                                                       counts, E);
        k_combine<<<ntiles, 256, 0, stream>>>(x, w_v, sums, counts, 1, out, bn);
        k_final<<<g4, 256, 0, stream>>>(out, bn, gamma, beta, pa);
    }
}